// Round 1
// baseline (274.897 us; speedup 1.0000x reference)
//
#include <hip/hip_runtime.h>

// proj_splat: project 48^3 voxel grid into 8 camera feature maps (64ch, 64x64),
// bilinear-sample, write (8, 64, 48^3) fp32.
//
// Constants fixed by the reference setup_inputs():
//   feats (8,64,64,64) f32, Kcam (2,4,3,4) f32, vmin/vmax (2,3) f32, nvox=48.
//   IM_H = IM_W = 256 -> rsz = 64/256 = 0.25.

#define NR    8
#define FDIM  64
#define FH    64
#define FW    64
#define NVOX  48
#define NV    (NVOX * NVOX * NVOX)   // 110592
#define VIEW  4

__global__ __launch_bounds__(256) void proj_splat_kernel(
    const float* __restrict__ feats,   // [NR][FDIM][FH*FW]
    const float* __restrict__ Kcam,    // [2][4][3][4] -> r*12
    const float* __restrict__ vmax,    // [2][3]
    const float* __restrict__ vmin,    // [2][3]
    float* __restrict__ out)           // [NR][FDIM][NV]
{
    const int r = blockIdx.y;                       // camera index 0..7
    const int n = blockIdx.x * 256 + threadIdx.x;   // voxel flat index
    const int b = r >> 2;                           // batch = r / VIEW

    // voxel (i,j,k): n = (i*NVOX + j)*NVOX + k  (x outermost, z innermost)
    const int i   = n / (NVOX * NVOX);
    const int rem = n - i * (NVOX * NVOX);
    const int j   = rem / NVOX;
    const int k   = rem - j * NVOX;

    const float inv = 1.0f / (float)(NVOX - 1);
    const float tx = (float)i * inv;
    const float ty = (float)j * inv;
    const float tz = (float)k * inv;

    const float* vmn = vmin + b * 3;
    const float* vmx = vmax + b * 3;
    const float gx = vmn[0] + (vmx[0] - vmn[0]) * tx;
    const float gy = vmn[1] + (vmx[1] - vmn[1]) * ty;
    const float gz = vmn[2] + (vmx[2] - vmn[2]) * tz;

    // im_p = Kcam[b][v] @ [gx, gy, gz, 1]
    const float* K = Kcam + r * 12;
    const float px = K[0] * gx + K[1] * gy + K[2]  * gz + K[3];
    const float py = K[4] * gx + K[5] * gy + K[6]  * gz + K[7];
    const float pz = K[8] * gx + K[9] * gy + K[10] * gz + K[11];

    const float rsz_w = (float)FW / 256.0f;   // 0.25
    const float rsz_h = (float)FH / 256.0f;   // 0.25

    float imx = px / pz * rsz_w;
    float imy = py / pz * rsz_h;
    imx = fminf(fmaxf(imx, 0.0f), (float)(FW - 1));
    imy = fminf(fmaxf(imy, 0.0f), (float)(FH - 1));

    // Reference semantics, literally: floor, then clipped +1 for the far sample.
    const float x0 = floorf(imx);
    const float x1 = fminf(x0 + 1.0f, (float)(FW - 1));
    const float y0 = floorf(imy);
    const float y1 = fminf(y0 + 1.0f, (float)(FH - 1));

    const float wa = (x1 - imx) * (y1 - imy);
    const float wb = (x1 - imx) * (imy - y0);
    const float wc = (imx - x0) * (y1 - imy);
    const float wd = (imx - x0) * (imy - y0);

    const int ix0 = (int)x0, ix1 = (int)x1;
    const int iy0 = (int)y0, iy1 = (int)y1;
    const int i00 = iy0 * FW + ix0;   // Ia
    const int i10 = iy1 * FW + ix0;   // Ib
    const int i01 = iy0 * FW + ix1;   // Ic
    const int i11 = iy1 * FW + ix1;   // Id

    const float* f = feats + (size_t)r * FDIM * FH * FW;
    float* o = out + (size_t)r * FDIM * NV + n;

#pragma unroll 4
    for (int c = 0; c < FDIM; ++c) {
        const float* fc = f + c * (FH * FW);
        const float Ia = fc[i00];
        const float Ib = fc[i10];
        const float Ic = fc[i01];
        const float Id = fc[i11];
        const float v = wa * Ia + wb * Ib + wc * Ic + wd * Id;
        __builtin_nontemporal_store(v, o + (size_t)c * NV);
    }
}

extern "C" void kernel_launch(void* const* d_in, const int* in_sizes, int n_in,
                              void* d_out, int out_size, void* d_ws, size_t ws_size,
                              hipStream_t stream) {
    const float* feats = (const float*)d_in[0];
    const float* Kcam  = (const float*)d_in[1];
    const float* vmax  = (const float*)d_in[2];
    const float* vmin  = (const float*)d_in[3];
    // d_in[4] = nvox (48) — fixed by setup, baked in as NVOX.
    float* out = (float*)d_out;

    dim3 grid(NV / 256, NR);   // 432 x 8 blocks, exact cover
    dim3 block(256);
    proj_splat_kernel<<<grid, block, 0, stream>>>(feats, Kcam, vmax, vmin, out);
}